// Round 10
// baseline (411.412 us; speedup 1.0000x reference)
//
#include <hip/hip_runtime.h>
#include <math.h>

#define DD 128
#define COUT 40
#define BN_EPS 1e-5f
#define L2_EPS 1e-12f
#define NREP 64            // stats replicas (atomic-contention spreading)

typedef __attribute__((ext_vector_type(8))) short bf16x8;
typedef __attribute__((ext_vector_type(4))) float f32x4;

static __device__ inline unsigned short f2bf(float f) {
    unsigned int x = __float_as_uint(f);
    unsigned int r = (x + 0x7FFFu + ((x >> 16) & 1u)) >> 16;   // RNE
    return (unsigned short)r;
}
static __device__ inline float bf2f(unsigned short u) {
    return __uint_as_float(((unsigned int)u) << 16);
}

// ---------------- setup kernels ----------------

// deg[] zeroed by k_wrepack_all (runs before). pord[i] = rank of edge i in its dst bucket.
__global__ void k_hist(const int* __restrict__ ei, int E, int* __restrict__ deg,
                       int* __restrict__ pord) {
    int i = blockIdx.x * blockDim.x + threadIdx.x;
    if (i < E) pord[i] = atomicAdd(&deg[ei[E + i]], 1);
}

// local (per-block) exclusive scan over deg (REAL edges only); also dinv = rsqrt(deg+1).
// Global fixup term boff[idx>>8] is applied on the fly by k_fill / k_aggs.
__global__ void k_scan_a(const int* __restrict__ deg, int* __restrict__ row_ptr,
                         int* __restrict__ bsum, float* __restrict__ dinv, int n) {
    __shared__ int s[256];
    int t = threadIdx.x;
    int idx = blockIdx.x * 256 + t;
    int v = (idx < n) ? deg[idx] : 0;
    if (idx < n) dinv[idx] = rsqrtf((float)(v + 1));   // +1 = self loop (norm only)
    s[t] = v; __syncthreads();
    for (int off = 1; off < 256; off <<= 1) {
        int x = (t >= off) ? s[t - off] : 0;
        __syncthreads(); s[t] += x; __syncthreads();
    }
    if (idx <= n) row_ptr[idx] = s[t] - v;     // local exclusive
    if (t == 255) bsum[blockIdx.x] = s[255];
}

__global__ void k_scan_b(const int* __restrict__ bsum, int* __restrict__ boff, int nb) {
    __shared__ int s[512];
    int t = threadIdx.x;
    int v = (t < nb) ? bsum[t] : 0;
    s[t] = v; __syncthreads();
    for (int off = 1; off < 512; off <<= 1) {
        int x = (t >= off) ? s[t - off] : 0;
        __syncthreads(); s[t] += x; __syncthreads();
    }
    if (t < nb) boff[t] = s[t] - v;            // exclusive block offsets
}

// pure scatter store, no atomics: perm[rp(v) + pord[i]] = src (real edges only).
__global__ void k_fill(const int* __restrict__ ei, const int* __restrict__ pord,
                       int E, const int* __restrict__ row_ptr,
                       const int* __restrict__ boff, int* __restrict__ perm) {
    int i = blockIdx.x * blockDim.x + threadIdx.x;
    if (i >= E) return;
    int u = ei[i];
    int v = ei[E + i];
    int pos = row_ptr[v] + boff[v >> 8] + pord[i];
    perm[pos] = u;
}

// One dispatch: repack W1/W2/W3 (blocks 0..23), Wout (24..26),
// zero stats + deg (27..34).
__global__ void k_wrepack_all(const float* __restrict__ W1, const float* __restrict__ W2,
                              const float* __restrict__ W3, const float* __restrict__ Wout,
                              unsigned short* __restrict__ wb,    // 3 * 16384
                              unsigned short* __restrict__ wob,   // 6144
                              float* __restrict__ stats,          // 3 * NREP * 256
                              int* __restrict__ deg, int n) {
    int b = blockIdx.x;
    if (b < 24) {
        int wi = b >> 3;
        const float* W = (wi == 0) ? W1 : (wi == 1) ? W2 : W3;
        unsigned short* out = wb + wi * 16384;
        int idx = (b & 7) * 256 + threadIdx.x;      // 0..2047
        int kc = idx >> 9;
        int cc = (idx >> 6) & 7;
        int lane = idx & 63;
        int nn = cc * 16 + (lane & 15);
        int kb = kc * 32 + (lane >> 4) * 8;
        unsigned short tmp[8];
#pragma unroll
        for (int j = 0; j < 8; j++) tmp[j] = f2bf(W[(size_t)(kb + j) * DD + nn]);
        *(uint4*)&out[(size_t)idx * 8] = *(const uint4*)tmp;
    } else if (b < 27) {
        int idx = (b - 24) * 256 + threadIdx.x;     // 0..767
        int kc = idx / 192;
        int rem = idx % 192;
        int cc = rem >> 6;
        int lane = rem & 63;
        int nn = cc * 16 + (lane & 15);
        int kb = kc * 32 + (lane >> 4) * 8;
        unsigned short tmp[8];
#pragma unroll
        for (int j = 0; j < 8; j++)
            tmp[j] = (nn < COUT) ? f2bf(Wout[(size_t)(kb + j) * COUT + nn]) : 0;
        *(uint4*)&wob[(size_t)idx * 8] = *(const uint4*)tmp;
    } else {
        int idx = (b - 27) * 256 + threadIdx.x;     // 0..2047, 8 blocks
        float4 z = make_float4(0.f, 0.f, 0.f, 0.f);
        for (int i = idx; i < 3 * NREP * 64; i += 8 * 256)
            ((float4*)stats)[i] = z;
        int4 iz = make_int4(0, 0, 0, 0);
        for (int i = idx; i < (n >> 2); i += 8 * 256)
            ((int4*)deg)[i] = iz;
        if (b == 27 && threadIdx.x < (n & 3)) deg[(n & ~3) + threadIdx.x] = 0;
    }
}

// ---------------- compute kernels ----------------

// linb(bf16) = dinv[row] * (x(fp32) @ W1) via MFMA. Pre-scaled for aggregation.
__global__ __launch_bounds__(256) void k_gemm0(const float* __restrict__ A,
                                               const unsigned short* __restrict__ Wb,
                                               const float* __restrict__ dinv,
                                               unsigned short* __restrict__ C, int nrows) {
    __shared__ __align__(16) unsigned short Ws[16384];   // 32 KB
    const int tid = threadIdx.x;
    for (int i = tid; i < 2048; i += 256)
        ((uint4*)Ws)[i] = ((const uint4*)Wb)[i];
    __syncthreads();

    const int wv = tid >> 6;
    const int lane = tid & 63;
    const int R0 = blockIdx.x * 64 + wv * 16;
    if (R0 >= nrows) return;
    const int m = lane & 15, q = lane >> 4;
    int rr = R0 + m; if (rr >= nrows) rr = nrows - 1;
    const float* Ar = A + (size_t)rr * DD + q * 8;

    bf16x8 af[4];
#pragma unroll
    for (int kc = 0; kc < 4; kc++) {
        float4 lo = *(const float4*)(Ar + kc * 32);
        float4 hi = *(const float4*)(Ar + kc * 32 + 4);
        unsigned short t[8];
        t[0] = f2bf(lo.x); t[1] = f2bf(lo.y); t[2] = f2bf(lo.z); t[3] = f2bf(lo.w);
        t[4] = f2bf(hi.x); t[5] = f2bf(hi.y); t[6] = f2bf(hi.z); t[7] = f2bf(hi.w);
        af[kc] = *(const bf16x8*)t;
    }

    f32x4 acc[8];
#pragma unroll
    for (int cc = 0; cc < 8; cc++) acc[cc] = (f32x4){0.f, 0.f, 0.f, 0.f};
#pragma unroll
    for (int kc = 0; kc < 4; kc++)
#pragma unroll
        for (int cc = 0; cc < 8; cc++) {
            bf16x8 b = *(const bf16x8*)&Ws[(size_t)((kc * 8 + cc) * 64 + lane) * 8];
            acc[cc] = __builtin_amdgcn_mfma_f32_16x16x32_bf16(af[kc], b, acc[cc], 0, 0, 0);
        }

    float dr[4];
#pragma unroll
    for (int i = 0; i < 4; i++) {
        int r = R0 + q * 4 + i;
        dr[i] = (r < nrows) ? dinv[r] : 0.f;
    }
#pragma unroll
    for (int cc = 0; cc < 8; cc++)
#pragma unroll
        for (int i = 0; i < 4; i++) {
            int r = R0 + q * 4 + i;
            if (r < nrows) C[(size_t)r * DD + cc * 16 + m] = f2bf(acc[cc][i] * dr[i]);
        }
}

// Aggregation + fused BN-stats. One node per HALF-WAVE. lin rows pre-scaled by
// dinv[src]; self-loop handled by initializing from the node's OWN row
// (sequential read, not a random gather). 2 slots x 16 lanes x 16B, unroll 4
// -> 8 edges in flight per node. out[v] = dv * sum + bias.
// perm stream is nontemporal (read-once; don't evict lin lines from L2).
__global__ __launch_bounds__(256) void k_aggs(const unsigned short* __restrict__ lin,
                                              const int* __restrict__ row_ptr,
                                              const int* __restrict__ boff,
                                              const int* __restrict__ perm,
                                              const float* __restrict__ dinv,
                                              const float* __restrict__ bias,
                                              unsigned short* __restrict__ outb,
                                              float* __restrict__ stats, int n) {
    const int tid = threadIdx.x;
    const int wv = tid >> 6;
    const int lane = tid & 63;
    const int half = lane >> 5;
    const int li = lane & 31;
    const int slot = li >> 4;         // 0 / 1
    const int ci = (li & 15) * 8;     // col base, 8 cols per lane

    const int v = blockIdx.x * 8 + wv * 2 + half;
    const bool valid = v < n;

    float acc[8];
#pragma unroll
    for (int k = 0; k < 8; k++) acc[k] = 0.f;
    float dv = 0.f;

    if (valid) {
        const int s0 = row_ptr[v] + boff[v >> 8];
        const int e0 = row_ptr[v + 1] + boff[(v + 1) >> 8];
        dv = dinv[v];
        if (slot == 0) {               // self loop: own (pre-scaled) row
            uint4 t = *(const uint4*)&lin[(size_t)v * DD + ci];
            acc[0] = __uint_as_float(t.x << 16);
            acc[1] = __uint_as_float(t.x & 0xFFFF0000u);
            acc[2] = __uint_as_float(t.y << 16);
            acc[3] = __uint_as_float(t.y & 0xFFFF0000u);
            acc[4] = __uint_as_float(t.z << 16);
            acc[5] = __uint_as_float(t.z & 0xFFFF0000u);
            acc[6] = __uint_as_float(t.w << 16);
            acc[7] = __uint_as_float(t.w & 0xFFFF0000u);
        }
        for (int j = s0; j < e0; j += 8) {
            int i0 = j + slot;
            int i1 = j + 2 + slot;
            int i2 = j + 4 + slot;
            int i3 = j + 6 + slot;
            bool b0 = i0 < e0, b1 = i1 < e0, b2 = i2 < e0, b3 = i3 < e0;
            int u0, u1, u2, u3;
            if (b0) u0 = __builtin_nontemporal_load(&perm[i0]);
            if (b1) u1 = __builtin_nontemporal_load(&perm[i1]);
            if (b2) u2 = __builtin_nontemporal_load(&perm[i2]);
            if (b3) u3 = __builtin_nontemporal_load(&perm[i3]);
            uint4 t0, t1, t2, t3;
            if (b0) t0 = *(const uint4*)&lin[(size_t)u0 * DD + ci];
            if (b1) t1 = *(const uint4*)&lin[(size_t)u1 * DD + ci];
            if (b2) t2 = *(const uint4*)&lin[(size_t)u2 * DD + ci];
            if (b3) t3 = *(const uint4*)&lin[(size_t)u3 * DD + ci];
            if (b0) {
                acc[0] += __uint_as_float(t0.x << 16);
                acc[1] += __uint_as_float(t0.x & 0xFFFF0000u);
                acc[2] += __uint_as_float(t0.y << 16);
                acc[3] += __uint_as_float(t0.y & 0xFFFF0000u);
                acc[4] += __uint_as_float(t0.z << 16);
                acc[5] += __uint_as_float(t0.z & 0xFFFF0000u);
                acc[6] += __uint_as_float(t0.w << 16);
                acc[7] += __uint_as_float(t0.w & 0xFFFF0000u);
            }
            if (b1) {
                acc[0] += __uint_as_float(t1.x << 16);
                acc[1] += __uint_as_float(t1.x & 0xFFFF0000u);
                acc[2] += __uint_as_float(t1.y << 16);
                acc[3] += __uint_as_float(t1.y & 0xFFFF0000u);
                acc[4] += __uint_as_float(t1.z << 16);
                acc[5] += __uint_as_float(t1.z & 0xFFFF0000u);
                acc[6] += __uint_as_float(t1.w << 16);
                acc[7] += __uint_as_float(t1.w & 0xFFFF0000u);
            }
            if (b2) {
                acc[0] += __uint_as_float(t2.x << 16);
                acc[1] += __uint_as_float(t2.x & 0xFFFF0000u);
                acc[2] += __uint_as_float(t2.y << 16);
                acc[3] += __uint_as_float(t2.y & 0xFFFF0000u);
                acc[4] += __uint_as_float(t2.z << 16);
                acc[5] += __uint_as_float(t2.z & 0xFFFF0000u);
                acc[6] += __uint_as_float(t2.w << 16);
                acc[7] += __uint_as_float(t2.w & 0xFFFF0000u);
            }
            if (b3) {
                acc[0] += __uint_as_float(t3.x << 16);
                acc[1] += __uint_as_float(t3.x & 0xFFFF0000u);
                acc[2] += __uint_as_float(t3.y << 16);
                acc[3] += __uint_as_float(t3.y & 0xFFFF0000u);
                acc[4] += __uint_as_float(t3.z << 16);
                acc[5] += __uint_as_float(t3.z & 0xFFFF0000u);
                acc[6] += __uint_as_float(t3.w << 16);
                acc[7] += __uint_as_float(t3.w & 0xFFFF0000u);
            }
        }
    }
    // combine the 2 slot partials (lanes l <-> l^16 within each half)
#pragma unroll
    for (int k = 0; k < 8; k++) acc[k] += __shfl_xor(acc[k], 16, 64);

    __shared__ float sh[8][128];
    __shared__ float qh[8][128];
    const int prow = wv * 2 + half;
    if (slot == 0) {
        if (valid) {
            float4 bb0 = *(const float4*)&bias[ci];
            float4 bb1 = *(const float4*)&bias[ci + 4];
            float bs[8] = {bb0.x, bb0.y, bb0.z, bb0.w, bb1.x, bb1.y, bb1.z, bb1.w};
            unsigned short t[8];
#pragma unroll
            for (int k = 0; k < 8; k++) {
                float a = acc[k] * dv + bs[k];
                t[k] = f2bf(a);
                sh[prow][ci + k] = a;
                qh[prow][ci + k] = a * a;
            }
            *(uint4*)&outb[(size_t)v * DD + ci] = *(const uint4*)t;
        } else {
#pragma unroll
            for (int k = 0; k < 8; k++) { sh[prow][ci + k] = 0.f; qh[prow][ci + k] = 0.f; }
        }
    }
    __syncthreads();
    if (tid < 128) {
        float a = 0.f, b = 0.f;
#pragma unroll
        for (int g = 0; g < 8; g++) { a += sh[g][tid]; b += qh[g][tid]; }
        float* st = stats + (size_t)(blockIdx.x & (NREP - 1)) * 256;
        atomicAdd(&st[tid], a);
        atomicAdd(&st[128 + tid], b);
    }
}

// Fused: h = l2norm(relu(bn(aggX)) [+ res]);  hbf_out = bf16(h);
// linb_out = dinv[row] * (h @ W)  (pre-scaled for aggregation).
template <bool HAS_RES>
__global__ __launch_bounds__(256) void k_fused(const unsigned short* __restrict__ aggX,
                                               const float* __restrict__ stats,
                                               const float* __restrict__ g,
                                               const float* __restrict__ be, float inv_n,
                                               const unsigned short* __restrict__ resb,
                                               const unsigned short* __restrict__ Wb,
                                               const float* __restrict__ dinv,
                                               unsigned short* __restrict__ hbf_out,
                                               unsigned short* __restrict__ linb_out,
                                               int nrows) {
    __shared__ __align__(16) unsigned short Ws[16384];
    __shared__ float ssl[256];          // scale / shift
    const int tid = threadIdx.x;
    for (int i = tid; i < 2048; i += 256)
        ((uint4*)Ws)[i] = ((const uint4*)Wb)[i];
    if (tid < 128) {
        float sa = 0.f, sb = 0.f;
        for (int r = 0; r < NREP; r++) {
            sa += stats[r * 256 + tid];
            sb += stats[r * 256 + 128 + tid];
        }
        float mu = sa * inv_n;
        float var = sb * inv_n - mu * mu;
        float sc = g[tid] * rsqrtf(var + BN_EPS);
        ssl[tid] = sc;
        ssl[128 + tid] = be[tid] - mu * sc;
    }
    __syncthreads();

    const int wv = tid >> 6;
    const int lane = tid & 63;
    const int R0 = blockIdx.x * 64 + wv * 16;
    if (R0 >= nrows) return;
    const int m = lane & 15, q = lane >> 4;
    int rr = R0 + m; if (rr >= nrows) rr = nrows - 1;
    const unsigned short* Ar = aggX + (size_t)rr * DD + q * 8;
    const unsigned short* Rr = HAS_RES ? resb + (size_t)rr * DD + q * 8 : nullptr;

    float y[4][8];
    float sq = 0.f;
#pragma unroll
    for (int kc = 0; kc < 4; kc++) {
        ushort4 lo = *(const ushort4*)(Ar + kc * 32);
        ushort4 hi = *(const ushort4*)(Ar + kc * 32 + 4);
        unsigned short av[8] = {lo.x, lo.y, lo.z, lo.w, hi.x, hi.y, hi.z, hi.w};
        int c0 = kc * 32 + q * 8;
        float4 sc0 = *(const float4*)&ssl[c0];
        float4 sc1 = *(const float4*)&ssl[c0 + 4];
        float4 sh0 = *(const float4*)&ssl[128 + c0];
        float4 sh1 = *(const float4*)&ssl[128 + c0 + 4];
        float scv[8] = {sc0.x, sc0.y, sc0.z, sc0.w, sc1.x, sc1.y, sc1.z, sc1.w};
        float shv[8] = {sh0.x, sh0.y, sh0.z, sh0.w, sh1.x, sh1.y, sh1.z, sh1.w};
        if (HAS_RES) {
            ushort4 rl = *(const ushort4*)(Rr + kc * 32);
            ushort4 rh = *(const ushort4*)(Rr + kc * 32 + 4);
            unsigned short rv[8] = {rl.x, rl.y, rl.z, rl.w, rh.x, rh.y, rh.z, rh.w};
#pragma unroll
            for (int j = 0; j < 8; j++) {
                float yy = fmaxf(bf2f(av[j]) * scv[j] + shv[j], 0.f) + bf2f(rv[j]);
                y[kc][j] = yy; sq += yy * yy;
            }
        } else {
#pragma unroll
            for (int j = 0; j < 8; j++) {
                float yy = fmaxf(bf2f(av[j]) * scv[j] + shv[j], 0.f);
                y[kc][j] = yy; sq += yy * yy;
            }
        }
    }
    sq += __shfl_xor(sq, 16, 64);
    sq += __shfl_xor(sq, 32, 64);
    float inv = 1.f / fmaxf(sqrtf(sq), L2_EPS);

    bf16x8 af[4];
#pragma unroll
    for (int kc = 0; kc < 4; kc++) {
        unsigned short t[8];
#pragma unroll
        for (int j = 0; j < 8; j++) t[j] = f2bf(y[kc][j] * inv);
        af[kc] = *(const bf16x8*)t;
        *(bf16x8*)&hbf_out[(size_t)rr * DD + q * 8 + kc * 32] = af[kc];
    }

    f32x4 acc[8];
#pragma unroll
    for (int cc = 0; cc < 8; cc++) acc[cc] = (f32x4){0.f, 0.f, 0.f, 0.f};
#pragma unroll
    for (int kc = 0; kc < 4; kc++)
#pragma unroll
        for (int cc = 0; cc < 8; cc++) {
            bf16x8 b = *(const bf16x8*)&Ws[(size_t)((kc * 8 + cc) * 64 + lane) * 8];
            acc[cc] = __builtin_amdgcn_mfma_f32_16x16x32_bf16(af[kc], b, acc[cc], 0, 0, 0);
        }

    float dr[4];
#pragma unroll
    for (int i = 0; i < 4; i++) {
        int r = R0 + q * 4 + i;
        dr[i] = (r < nrows) ? dinv[r] : 0.f;
    }
#pragma unroll
    for (int cc = 0; cc < 8; cc++)
#pragma unroll
        for (int i = 0; i < 4; i++) {
            int r = R0 + q * 4 + i;
            if (r < nrows) linb_out[(size_t)r * DD + cc * 16 + m] = f2bf(acc[cc][i] * dr[i]);
        }
}

// Fused output: h3 = l2norm(relu(bn(aggX)) + res);  out = h3 @ Wout + bout (fp32)
__global__ __launch_bounds__(256) void k_outfused(const unsigned short* __restrict__ aggX,
                                                  const float* __restrict__ stats,
                                                  const float* __restrict__ g,
                                                  const float* __restrict__ be, float inv_n,
                                                  const unsigned short* __restrict__ resb,
                                                  const unsigned short* __restrict__ wob,
                                                  const float* __restrict__ bout,
                                                  float* __restrict__ C, int nrows) {
    __shared__ __align__(16) unsigned short Ws[6144];
    __shared__ float ssl[256];
    const int tid = threadIdx.x;
    for (int i = tid; i < 768; i += 256)
        ((uint4*)Ws)[i] = ((const uint4*)wob)[i];
    if (tid < 128) {
        float sa = 0.f, sb = 0.f;
        for (int r = 0; r < NREP; r++) {
            sa += stats[r * 256 + tid];
            sb += stats[r * 256 + 128 + tid];
        }
        float mu = sa * inv_n;
        float var = sb * inv_n - mu * mu;
        float sc = g[tid] * rsqrtf(var + BN_EPS);
        ssl[tid] = sc;
        ssl[128 + tid] = be[tid] - mu * sc;
    }
    __syncthreads();

    const int wv = tid >> 6;
    const int lane = tid & 63;
    const int R0 = blockIdx.x * 64 + wv * 16;
    if (R0 >= nrows) return;
    const int m = lane & 15, q = lane >> 4;
    int rr = R0 + m; if (rr >= nrows) rr = nrows - 1;
    const unsigned short* Ar = aggX + (size_t)rr * DD + q * 8;
    const unsigned short* Rr = resb + (size_t)rr * DD + q * 8;

    float y[4][8];
    float sq = 0.f;
#pragma unroll
    for (int kc = 0; kc < 4; kc++) {
        ushort4 lo = *(const ushort4*)(Ar + kc * 32);
        ushort4 hi = *(const ushort4*)(Ar + kc * 32 + 4);
        ushort4 rl = *(const ushort4*)(Rr + kc * 32);
        ushort4 rh = *(const ushort4*)(Rr + kc * 32 + 4);
        unsigned short av[8] = {lo.x, lo.y, lo.z, lo.w, hi.x, hi.y, hi.z, hi.w};
        unsigned short rv[8] = {rl.x, rl.y, rl.z, rl.w, rh.x, rh.y, rh.z, rh.w};
        int c0 = kc * 32 + q * 8;
        float4 sc0 = *(const float4*)&ssl[c0];
        float4 sc1 = *(const float4*)&ssl[c0 + 4];
        float4 sh0 = *(const float4*)&ssl[128 + c0];
        float4 sh1 = *(const float4*)&ssl[128 + c0 + 4];
        float scv[8] = {sc0.x, sc0.y, sc0.z, sc0.w, sc1.x, sc1.y, sc1.z, sc1.w};
        float shv[8] = {sh0.x, sh0.y, sh0.z, sh0.w, sh1.x, sh1.y, sh1.z, sh1.w};
#pragma unroll
        for (int j = 0; j < 8; j++) {
            float yy = fmaxf(bf2f(av[j]) * scv[j] + shv[j], 0.f) + bf2f(rv[j]);
            y[kc][j] = yy; sq += yy * yy;
        }
    }
    sq += __shfl_xor(sq, 16, 64);
    sq += __shfl_xor(sq, 32, 64);
    float inv = 1.f / fmaxf(sqrtf(sq), L2_EPS);

    bf16x8 af[4];
#pragma unroll
    for (int kc = 0; kc < 4; kc++) {
        unsigned short t[8];
#pragma unroll
        for (int j = 0; j < 8; j++) t[j] = f2bf(y[kc][j] * inv);
        af[kc] = *(const bf16x8*)t;
    }

    f32x4 acc[3];
#pragma unroll
    for (int cc = 0; cc < 3; cc++) acc[cc] = (f32x4){0.f, 0.f, 0.f, 0.f};
#pragma unroll
    for (int kc = 0; kc < 4; kc++)
#pragma unroll
        for (int cc = 0; cc < 3; cc++) {
            bf16x8 b = *(const bf16x8*)&Ws[(size_t)((kc * 3 + cc) * 64 + lane) * 8];
            acc[cc] = __builtin_amdgcn_mfma_f32_16x16x32_bf16(af[kc], b, acc[cc], 0, 0, 0);
        }

#pragma unroll
    for (int cc = 0; cc < 3; cc++) {
        int col = cc * 16 + m;
        if (col < COUT) {
            float bb = bout[col];
#pragma unroll
            for (int i = 0; i < 4; i++) {
                int r = R0 + q * 4 + i;
                if (r < nrows) C[(size_t)r * COUT + col] = acc[cc][i] + bb;
            }
        }
    }
}

// ---------------- host ----------------

extern "C" void kernel_launch(void* const* d_in, const int* in_sizes, int n_in,
                              void* d_out, int out_size, void* d_ws, size_t ws_size,
                              hipStream_t stream) {
    const float* x    = (const float*)d_in[0];
    const int*   ei   = (const int*)d_in[1];
    const float* W1   = (const float*)d_in[2];
    const float* b1   = (const float*)d_in[3];
    const float* W2   = (const float*)d_in[4];
    const float* b2   = (const float*)d_in[5];
    const float* W3   = (const float*)d_in[6];
    const float* b3   = (const float*)d_in[7];
    const float* g1   = (const float*)d_in[8];
    const float* be1  = (const float*)d_in[9];
    const float* g2   = (const float*)d_in[10];
    const float* be2  = (const float*)d_in[11];
    const float* g3   = (const float*)d_in[12];
    const float* be3  = (const float*)d_in[13];
    const float* Wout = (const float*)d_in[14];
    const float* bout = (const float*)d_in[15];
    float* out = (float*)d_out;

    const int N = in_sizes[0] / DD;
    const int E = in_sizes[1] / 2;
    const int SSTRIDE = NREP * 256;          // floats per layer's stats

    // workspace layout
    char* w = (char*)d_ws;
    unsigned short* linb = (unsigned short*)w; w += (size_t)N * DD * sizeof(unsigned short);
    unsigned short* aggA = (unsigned short*)w; w += (size_t)N * DD * sizeof(unsigned short);
    unsigned short* aggB = (unsigned short*)w; w += (size_t)N * DD * sizeof(unsigned short);
    unsigned short* hbf1 = (unsigned short*)w; w += (size_t)N * DD * sizeof(unsigned short);
    unsigned short* hbf2 = (unsigned short*)w; w += (size_t)N * DD * sizeof(unsigned short);
    unsigned short* wb   = (unsigned short*)w; w += 3 * 16384 * sizeof(unsigned short);
    unsigned short* wob  = (unsigned short*)w; w += 6144 * sizeof(unsigned short);
    int* perm    = (int*)w;                    w += (size_t)E * sizeof(int);
    int* pord    = (int*)w;                    w += (size_t)E * sizeof(int);
    int* deg     = (int*)w;                    w += (size_t)N * sizeof(int);
    int* row_ptr = (int*)w;                    w += (size_t)(N + 1) * sizeof(int);
    float* dinv  = (float*)w;                  w += (size_t)N * sizeof(float);
    int* bsum    = (int*)w;                    w += 512 * sizeof(int);
    int* boff    = (int*)w;                    w += 512 * sizeof(int);
    float* stats = (float*)w;                  w += 3 * (size_t)SSTRIDE * sizeof(float);

    const int NB = (N + 1 + 255) / 256;      // scan blocks

    // ---- CSR build + weight repack (deg/stats zeroed inside wrepack) ----
    k_wrepack_all<<<35, 256, 0, stream>>>(W1, W2, W3, Wout, wb, wob, stats, deg, N);
    k_hist<<<(E + 255) / 256, 256, 0, stream>>>(ei, E, deg, pord);
    k_scan_a<<<NB, 256, 0, stream>>>(deg, row_ptr, bsum, dinv, N);
    k_scan_b<<<1, 512, 0, stream>>>(bsum, boff, NB);
    k_fill<<<(E + 255) / 256, 256, 0, stream>>>(ei, pord, E, row_ptr, boff, perm);

    int gemmGrid = (N + 63) / 64;
    int aggGrid = (N + 7) / 8;               // one node per half-wave
    float inv_n = 1.0f / (float)N;

    // ---- layer 1 ----
    k_gemm0<<<gemmGrid, 256, 0, stream>>>(x, wb, dinv, linb, N);
    k_aggs<<<aggGrid, 256, 0, stream>>>(linb, row_ptr, boff, perm, dinv, b1, aggA, stats, N);
    // ---- layer 2 (post1 fused into gemm2) ----
    k_fused<false><<<gemmGrid, 256, 0, stream>>>(aggA, stats, g1, be1, inv_n,
                                                 nullptr, wb + 16384, dinv, hbf1, linb, N);
    k_aggs<<<aggGrid, 256, 0, stream>>>(linb, row_ptr, boff, perm, dinv, b2, aggB,
                                        stats + SSTRIDE, N);
    // ---- layer 3 (post2 fused into gemm3) ----
    k_fused<true><<<gemmGrid, 256, 0, stream>>>(aggB, stats + SSTRIDE, g2, be2, inv_n,
                                                hbf1, wb + 32768, dinv, hbf2, linb, N);
    k_aggs<<<aggGrid, 256, 0, stream>>>(linb, row_ptr, boff, perm, dinv, b3, aggA,
                                        stats + 2 * SSTRIDE, N);
    // ---- output (post3 fused into output GEMM) ----
    k_outfused<<<gemmGrid, 256, 0, stream>>>(aggA, stats + 2 * SSTRIDE, g3, be3, inv_n,
                                             hbf2, wob, bout, out, N);
}

// Round 11
// 392.355 us; speedup vs baseline: 1.0486x; 1.0486x over previous
//
#include <hip/hip_runtime.h>
#include <math.h>

#define DD 128
#define COUT 40
#define BN_EPS 1e-5f
#define L2_EPS 1e-12f
#define NREP 64            // stats replicas (atomic-contention spreading)

typedef __attribute__((ext_vector_type(8))) short bf16x8;
typedef __attribute__((ext_vector_type(4))) float f32x4;

static __device__ inline unsigned short f2bf(float f) {
    unsigned int x = __float_as_uint(f);
    unsigned int r = (x + 0x7FFFu + ((x >> 16) & 1u)) >> 16;   // RNE
    return (unsigned short)r;
}
static __device__ inline float bf2f(unsigned short u) {
    return __uint_as_float(((unsigned int)u) << 16);
}

// ---------------- setup kernels ----------------

// deg[] zeroed by k_wrepack_all (runs before). pord[i] = rank of edge i in its dst bucket.
__global__ void k_hist(const int* __restrict__ ei, int E, int* __restrict__ deg,
                       int* __restrict__ pord) {
    int i = blockIdx.x * blockDim.x + threadIdx.x;
    if (i < E) pord[i] = atomicAdd(&deg[ei[E + i]], 1);
}

// local (per-block) exclusive scan over deg (REAL edges only); also dinv = rsqrt(deg+1).
// Global fixup term boff[idx>>8] is applied on the fly by k_fill / k_aggs.
__global__ void k_scan_a(const int* __restrict__ deg, int* __restrict__ row_ptr,
                         int* __restrict__ bsum, float* __restrict__ dinv, int n) {
    __shared__ int s[256];
    int t = threadIdx.x;
    int idx = blockIdx.x * 256 + t;
    int v = (idx < n) ? deg[idx] : 0;
    if (idx < n) dinv[idx] = rsqrtf((float)(v + 1));   // +1 = self loop (norm only)
    s[t] = v; __syncthreads();
    for (int off = 1; off < 256; off <<= 1) {
        int x = (t >= off) ? s[t - off] : 0;
        __syncthreads(); s[t] += x; __syncthreads();
    }
    if (idx <= n) row_ptr[idx] = s[t] - v;     // local exclusive
    if (t == 255) bsum[blockIdx.x] = s[255];
}

__global__ void k_scan_b(const int* __restrict__ bsum, int* __restrict__ boff, int nb) {
    __shared__ int s[512];
    int t = threadIdx.x;
    int v = (t < nb) ? bsum[t] : 0;
    s[t] = v; __syncthreads();
    for (int off = 1; off < 512; off <<= 1) {
        int x = (t >= off) ? s[t - off] : 0;
        __syncthreads(); s[t] += x; __syncthreads();
    }
    if (t < nb) boff[t] = s[t] - v;            // exclusive block offsets
}

// pure scatter store, no atomics: perm[rp(v) + pord[i]] = src (real edges only).
__global__ void k_fill(const int* __restrict__ ei, const int* __restrict__ pord,
                       int E, const int* __restrict__ row_ptr,
                       const int* __restrict__ boff, int* __restrict__ perm) {
    int i = blockIdx.x * blockDim.x + threadIdx.x;
    if (i >= E) return;
    int u = ei[i];
    int v = ei[E + i];
    int pos = row_ptr[v] + boff[v >> 8] + pord[i];
    perm[pos] = u;
}

// One dispatch: repack W1/W2/W3 (blocks 0..23), Wout (24..26),
// zero stats + deg (27..34).
__global__ void k_wrepack_all(const float* __restrict__ W1, const float* __restrict__ W2,
                              const float* __restrict__ W3, const float* __restrict__ Wout,
                              unsigned short* __restrict__ wb,    // 3 * 16384
                              unsigned short* __restrict__ wob,   // 6144
                              float* __restrict__ stats,          // 3 * NREP * 256
                              int* __restrict__ deg, int n) {
    int b = blockIdx.x;
    if (b < 24) {
        int wi = b >> 3;
        const float* W = (wi == 0) ? W1 : (wi == 1) ? W2 : W3;
        unsigned short* out = wb + wi * 16384;
        int idx = (b & 7) * 256 + threadIdx.x;      // 0..2047
        int kc = idx >> 9;
        int cc = (idx >> 6) & 7;
        int lane = idx & 63;
        int nn = cc * 16 + (lane & 15);
        int kb = kc * 32 + (lane >> 4) * 8;
        unsigned short tmp[8];
#pragma unroll
        for (int j = 0; j < 8; j++) tmp[j] = f2bf(W[(size_t)(kb + j) * DD + nn]);
        *(uint4*)&out[(size_t)idx * 8] = *(const uint4*)tmp;
    } else if (b < 27) {
        int idx = (b - 24) * 256 + threadIdx.x;     // 0..767
        int kc = idx / 192;
        int rem = idx % 192;
        int cc = rem >> 6;
        int lane = rem & 63;
        int nn = cc * 16 + (lane & 15);
        int kb = kc * 32 + (lane >> 4) * 8;
        unsigned short tmp[8];
#pragma unroll
        for (int j = 0; j < 8; j++)
            tmp[j] = (nn < COUT) ? f2bf(Wout[(size_t)(kb + j) * COUT + nn]) : 0;
        *(uint4*)&wob[(size_t)idx * 8] = *(const uint4*)tmp;
    } else {
        int idx = (b - 27) * 256 + threadIdx.x;     // 0..2047, 8 blocks
        float4 z = make_float4(0.f, 0.f, 0.f, 0.f);
        for (int i = idx; i < 3 * NREP * 64; i += 8 * 256)
            ((float4*)stats)[i] = z;
        int4 iz = make_int4(0, 0, 0, 0);
        for (int i = idx; i < (n >> 2); i += 8 * 256)
            ((int4*)deg)[i] = iz;
        if (b == 27 && threadIdx.x < (n & 3)) deg[(n & ~3) + threadIdx.x] = 0;
    }
}

// ---------------- compute kernels ----------------

// linb(bf16) = dinv[row] * (x(fp32) @ W1) via MFMA. Pre-scaled for aggregation.
__global__ __launch_bounds__(256) void k_gemm0(const float* __restrict__ A,
                                               const unsigned short* __restrict__ Wb,
                                               const float* __restrict__ dinv,
                                               unsigned short* __restrict__ C, int nrows) {
    __shared__ __align__(16) unsigned short Ws[16384];   // 32 KB
    const int tid = threadIdx.x;
    for (int i = tid; i < 2048; i += 256)
        ((uint4*)Ws)[i] = ((const uint4*)Wb)[i];
    __syncthreads();

    const int wv = tid >> 6;
    const int lane = tid & 63;
    const int R0 = blockIdx.x * 64 + wv * 16;
    if (R0 >= nrows) return;
    const int m = lane & 15, q = lane >> 4;
    int rr = R0 + m; if (rr >= nrows) rr = nrows - 1;
    const float* Ar = A + (size_t)rr * DD + q * 8;

    bf16x8 af[4];
#pragma unroll
    for (int kc = 0; kc < 4; kc++) {
        float4 lo = *(const float4*)(Ar + kc * 32);
        float4 hi = *(const float4*)(Ar + kc * 32 + 4);
        unsigned short t[8];
        t[0] = f2bf(lo.x); t[1] = f2bf(lo.y); t[2] = f2bf(lo.z); t[3] = f2bf(lo.w);
        t[4] = f2bf(hi.x); t[5] = f2bf(hi.y); t[6] = f2bf(hi.z); t[7] = f2bf(hi.w);
        af[kc] = *(const bf16x8*)t;
    }

    f32x4 acc[8];
#pragma unroll
    for (int cc = 0; cc < 8; cc++) acc[cc] = (f32x4){0.f, 0.f, 0.f, 0.f};
#pragma unroll
    for (int kc = 0; kc < 4; kc++)
#pragma unroll
        for (int cc = 0; cc < 8; cc++) {
            bf16x8 b = *(const bf16x8*)&Ws[(size_t)((kc * 8 + cc) * 64 + lane) * 8];
            acc[cc] = __builtin_amdgcn_mfma_f32_16x16x32_bf16(af[kc], b, acc[cc], 0, 0, 0);
        }

    float dr[4];
#pragma unroll
    for (int i = 0; i < 4; i++) {
        int r = R0 + q * 4 + i;
        dr[i] = (r < nrows) ? dinv[r] : 0.f;
    }
#pragma unroll
    for (int cc = 0; cc < 8; cc++)
#pragma unroll
        for (int i = 0; i < 4; i++) {
            int r = R0 + q * 4 + i;
            if (r < nrows) C[(size_t)r * DD + cc * 16 + m] = f2bf(acc[cc][i] * dr[i]);
        }
}

// Aggregation + fused BN-stats. One node per HALF-WAVE. lin rows pre-scaled by
// dinv[src]; self-loop handled by initializing from the node's OWN row
// (sequential read, not a random gather). 2 slots x 16 lanes x 16B, unroll 4
// -> 8 edges in flight per node. out[v] = dv * sum + bias.
__global__ __launch_bounds__(256) void k_aggs(const unsigned short* __restrict__ lin,
                                              const int* __restrict__ row_ptr,
                                              const int* __restrict__ boff,
                                              const int* __restrict__ perm,
                                              const float* __restrict__ dinv,
                                              const float* __restrict__ bias,
                                              unsigned short* __restrict__ outb,
                                              float* __restrict__ stats, int n) {
    const int tid = threadIdx.x;
    const int wv = tid >> 6;
    const int lane = tid & 63;
    const int half = lane >> 5;
    const int li = lane & 31;
    const int slot = li >> 4;         // 0 / 1
    const int ci = (li & 15) * 8;     // col base, 8 cols per lane

    const int v = blockIdx.x * 8 + wv * 2 + half;
    const bool valid = v < n;

    float acc[8];
#pragma unroll
    for (int k = 0; k < 8; k++) acc[k] = 0.f;
    float dv = 0.f;

    if (valid) {
        const int s0 = row_ptr[v] + boff[v >> 8];
        const int e0 = row_ptr[v + 1] + boff[(v + 1) >> 8];
        dv = dinv[v];
        if (slot == 0) {               // self loop: own (pre-scaled) row
            uint4 t = *(const uint4*)&lin[(size_t)v * DD + ci];
            acc[0] = __uint_as_float(t.x << 16);
            acc[1] = __uint_as_float(t.x & 0xFFFF0000u);
            acc[2] = __uint_as_float(t.y << 16);
            acc[3] = __uint_as_float(t.y & 0xFFFF0000u);
            acc[4] = __uint_as_float(t.z << 16);
            acc[5] = __uint_as_float(t.z & 0xFFFF0000u);
            acc[6] = __uint_as_float(t.w << 16);
            acc[7] = __uint_as_float(t.w & 0xFFFF0000u);
        }
        for (int j = s0; j < e0; j += 8) {
            int i0 = j + slot;
            int i1 = j + 2 + slot;
            int i2 = j + 4 + slot;
            int i3 = j + 6 + slot;
            bool b0 = i0 < e0, b1 = i1 < e0, b2 = i2 < e0, b3 = i3 < e0;
            int u0, u1, u2, u3;
            if (b0) u0 = perm[i0];
            if (b1) u1 = perm[i1];
            if (b2) u2 = perm[i2];
            if (b3) u3 = perm[i3];
            uint4 t0, t1, t2, t3;
            if (b0) t0 = *(const uint4*)&lin[(size_t)u0 * DD + ci];
            if (b1) t1 = *(const uint4*)&lin[(size_t)u1 * DD + ci];
            if (b2) t2 = *(const uint4*)&lin[(size_t)u2 * DD + ci];
            if (b3) t3 = *(const uint4*)&lin[(size_t)u3 * DD + ci];
            if (b0) {
                acc[0] += __uint_as_float(t0.x << 16);
                acc[1] += __uint_as_float(t0.x & 0xFFFF0000u);
                acc[2] += __uint_as_float(t0.y << 16);
                acc[3] += __uint_as_float(t0.y & 0xFFFF0000u);
                acc[4] += __uint_as_float(t0.z << 16);
                acc[5] += __uint_as_float(t0.z & 0xFFFF0000u);
                acc[6] += __uint_as_float(t0.w << 16);
                acc[7] += __uint_as_float(t0.w & 0xFFFF0000u);
            }
            if (b1) {
                acc[0] += __uint_as_float(t1.x << 16);
                acc[1] += __uint_as_float(t1.x & 0xFFFF0000u);
                acc[2] += __uint_as_float(t1.y << 16);
                acc[3] += __uint_as_float(t1.y & 0xFFFF0000u);
                acc[4] += __uint_as_float(t1.z << 16);
                acc[5] += __uint_as_float(t1.z & 0xFFFF0000u);
                acc[6] += __uint_as_float(t1.w << 16);
                acc[7] += __uint_as_float(t1.w & 0xFFFF0000u);
            }
            if (b2) {
                acc[0] += __uint_as_float(t2.x << 16);
                acc[1] += __uint_as_float(t2.x & 0xFFFF0000u);
                acc[2] += __uint_as_float(t2.y << 16);
                acc[3] += __uint_as_float(t2.y & 0xFFFF0000u);
                acc[4] += __uint_as_float(t2.z << 16);
                acc[5] += __uint_as_float(t2.z & 0xFFFF0000u);
                acc[6] += __uint_as_float(t2.w << 16);
                acc[7] += __uint_as_float(t2.w & 0xFFFF0000u);
            }
            if (b3) {
                acc[0] += __uint_as_float(t3.x << 16);
                acc[1] += __uint_as_float(t3.x & 0xFFFF0000u);
                acc[2] += __uint_as_float(t3.y << 16);
                acc[3] += __uint_as_float(t3.y & 0xFFFF0000u);
                acc[4] += __uint_as_float(t3.z << 16);
                acc[5] += __uint_as_float(t3.z & 0xFFFF0000u);
                acc[6] += __uint_as_float(t3.w << 16);
                acc[7] += __uint_as_float(t3.w & 0xFFFF0000u);
            }
        }
    }
    // combine the 2 slot partials (lanes l <-> l^16 within each half)
#pragma unroll
    for (int k = 0; k < 8; k++) acc[k] += __shfl_xor(acc[k], 16, 64);

    __shared__ float sh[8][128];
    __shared__ float qh[8][128];
    const int prow = wv * 2 + half;
    if (slot == 0) {
        if (valid) {
            float4 bb0 = *(const float4*)&bias[ci];
            float4 bb1 = *(const float4*)&bias[ci + 4];
            float bs[8] = {bb0.x, bb0.y, bb0.z, bb0.w, bb1.x, bb1.y, bb1.z, bb1.w};
            unsigned short t[8];
#pragma unroll
            for (int k = 0; k < 8; k++) {
                float a = acc[k] * dv + bs[k];
                t[k] = f2bf(a);
                sh[prow][ci + k] = a;
                qh[prow][ci + k] = a * a;
            }
            *(uint4*)&outb[(size_t)v * DD + ci] = *(const uint4*)t;
        } else {
#pragma unroll
            for (int k = 0; k < 8; k++) { sh[prow][ci + k] = 0.f; qh[prow][ci + k] = 0.f; }
        }
    }
    __syncthreads();
    if (tid < 128) {
        float a = 0.f, b = 0.f;
#pragma unroll
        for (int g = 0; g < 8; g++) { a += sh[g][tid]; b += qh[g][tid]; }
        float* st = stats + (size_t)(blockIdx.x & (NREP - 1)) * 256;
        atomicAdd(&st[tid], a);
        atomicAdd(&st[128 + tid], b);
    }
}

// Fused: h = l2norm(relu(bn(aggX)) [+ res]);  hbf_out = bf16(h);
// linb_out = dinv[row] * (h @ W)  (pre-scaled for aggregation).
template <bool HAS_RES>
__global__ __launch_bounds__(256) void k_fused(const unsigned short* __restrict__ aggX,
                                               const float* __restrict__ stats,
                                               const float* __restrict__ g,
                                               const float* __restrict__ be, float inv_n,
                                               const unsigned short* __restrict__ resb,
                                               const unsigned short* __restrict__ Wb,
                                               const float* __restrict__ dinv,
                                               unsigned short* __restrict__ hbf_out,
                                               unsigned short* __restrict__ linb_out,
                                               int nrows) {
    __shared__ __align__(16) unsigned short Ws[16384];
    __shared__ float ssl[256];          // scale / shift
    const int tid = threadIdx.x;
    for (int i = tid; i < 2048; i += 256)
        ((uint4*)Ws)[i] = ((const uint4*)Wb)[i];
    if (tid < 128) {
        float sa = 0.f, sb = 0.f;
        for (int r = 0; r < NREP; r++) {
            sa += stats[r * 256 + tid];
            sb += stats[r * 256 + 128 + tid];
        }
        float mu = sa * inv_n;
        float var = sb * inv_n - mu * mu;
        float sc = g[tid] * rsqrtf(var + BN_EPS);
        ssl[tid] = sc;
        ssl[128 + tid] = be[tid] - mu * sc;
    }
    __syncthreads();

    const int wv = tid >> 6;
    const int lane = tid & 63;
    const int R0 = blockIdx.x * 64 + wv * 16;
    if (R0 >= nrows) return;
    const int m = lane & 15, q = lane >> 4;
    int rr = R0 + m; if (rr >= nrows) rr = nrows - 1;
    const unsigned short* Ar = aggX + (size_t)rr * DD + q * 8;
    const unsigned short* Rr = HAS_RES ? resb + (size_t)rr * DD + q * 8 : nullptr;

    float y[4][8];
    float sq = 0.f;
#pragma unroll
    for (int kc = 0; kc < 4; kc++) {
        ushort4 lo = *(const ushort4*)(Ar + kc * 32);
        ushort4 hi = *(const ushort4*)(Ar + kc * 32 + 4);
        unsigned short av[8] = {lo.x, lo.y, lo.z, lo.w, hi.x, hi.y, hi.z, hi.w};
        int c0 = kc * 32 + q * 8;
        float4 sc0 = *(const float4*)&ssl[c0];
        float4 sc1 = *(const float4*)&ssl[c0 + 4];
        float4 sh0 = *(const float4*)&ssl[128 + c0];
        float4 sh1 = *(const float4*)&ssl[128 + c0 + 4];
        float scv[8] = {sc0.x, sc0.y, sc0.z, sc0.w, sc1.x, sc1.y, sc1.z, sc1.w};
        float shv[8] = {sh0.x, sh0.y, sh0.z, sh0.w, sh1.x, sh1.y, sh1.z, sh1.w};
        if (HAS_RES) {
            ushort4 rl = *(const ushort4*)(Rr + kc * 32);
            ushort4 rh = *(const ushort4*)(Rr + kc * 32 + 4);
            unsigned short rv[8] = {rl.x, rl.y, rl.z, rl.w, rh.x, rh.y, rh.z, rh.w};
#pragma unroll
            for (int j = 0; j < 8; j++) {
                float yy = fmaxf(bf2f(av[j]) * scv[j] + shv[j], 0.f) + bf2f(rv[j]);
                y[kc][j] = yy; sq += yy * yy;
            }
        } else {
#pragma unroll
            for (int j = 0; j < 8; j++) {
                float yy = fmaxf(bf2f(av[j]) * scv[j] + shv[j], 0.f);
                y[kc][j] = yy; sq += yy * yy;
            }
        }
    }
    sq += __shfl_xor(sq, 16, 64);
    sq += __shfl_xor(sq, 32, 64);
    float inv = 1.f / fmaxf(sqrtf(sq), L2_EPS);

    bf16x8 af[4];
#pragma unroll
    for (int kc = 0; kc < 4; kc++) {
        unsigned short t[8];
#pragma unroll
        for (int j = 0; j < 8; j++) t[j] = f2bf(y[kc][j] * inv);
        af[kc] = *(const bf16x8*)t;
        *(bf16x8*)&hbf_out[(size_t)rr * DD + q * 8 + kc * 32] = af[kc];
    }

    f32x4 acc[8];
#pragma unroll
    for (int cc = 0; cc < 8; cc++) acc[cc] = (f32x4){0.f, 0.f, 0.f, 0.f};
#pragma unroll
    for (int kc = 0; kc < 4; kc++)
#pragma unroll
        for (int cc = 0; cc < 8; cc++) {
            bf16x8 b = *(const bf16x8*)&Ws[(size_t)((kc * 8 + cc) * 64 + lane) * 8];
            acc[cc] = __builtin_amdgcn_mfma_f32_16x16x32_bf16(af[kc], b, acc[cc], 0, 0, 0);
        }

    float dr[4];
#pragma unroll
    for (int i = 0; i < 4; i++) {
        int r = R0 + q * 4 + i;
        dr[i] = (r < nrows) ? dinv[r] : 0.f;
    }
#pragma unroll
    for (int cc = 0; cc < 8; cc++)
#pragma unroll
        for (int i = 0; i < 4; i++) {
            int r = R0 + q * 4 + i;
            if (r < nrows) linb_out[(size_t)r * DD + cc * 16 + m] = f2bf(acc[cc][i] * dr[i]);
        }
}

// Fused output: h3 = l2norm(relu(bn(aggX)) + res);  out = h3 @ Wout + bout (fp32)
__global__ __launch_bounds__(256) void k_outfused(const unsigned short* __restrict__ aggX,
                                                  const float* __restrict__ stats,
                                                  const float* __restrict__ g,
                                                  const float* __restrict__ be, float inv_n,
                                                  const unsigned short* __restrict__ resb,
                                                  const unsigned short* __restrict__ wob,
                                                  const float* __restrict__ bout,
                                                  float* __restrict__ C, int nrows) {
    __shared__ __align__(16) unsigned short Ws[6144];
    __shared__ float ssl[256];
    const int tid = threadIdx.x;
    for (int i = tid; i < 768; i += 256)
        ((uint4*)Ws)[i] = ((const uint4*)wob)[i];
    if (tid < 128) {
        float sa = 0.f, sb = 0.f;
        for (int r = 0; r < NREP; r++) {
            sa += stats[r * 256 + tid];
            sb += stats[r * 256 + 128 + tid];
        }
        float mu = sa * inv_n;
        float var = sb * inv_n - mu * mu;
        float sc = g[tid] * rsqrtf(var + BN_EPS);
        ssl[tid] = sc;
        ssl[128 + tid] = be[tid] - mu * sc;
    }
    __syncthreads();

    const int wv = tid >> 6;
    const int lane = tid & 63;
    const int R0 = blockIdx.x * 64 + wv * 16;
    if (R0 >= nrows) return;
    const int m = lane & 15, q = lane >> 4;
    int rr = R0 + m; if (rr >= nrows) rr = nrows - 1;
    const unsigned short* Ar = aggX + (size_t)rr * DD + q * 8;
    const unsigned short* Rr = resb + (size_t)rr * DD + q * 8;

    float y[4][8];
    float sq = 0.f;
#pragma unroll
    for (int kc = 0; kc < 4; kc++) {
        ushort4 lo = *(const ushort4*)(Ar + kc * 32);
        ushort4 hi = *(const ushort4*)(Ar + kc * 32 + 4);
        ushort4 rl = *(const ushort4*)(Rr + kc * 32);
        ushort4 rh = *(const ushort4*)(Rr + kc * 32 + 4);
        unsigned short av[8] = {lo.x, lo.y, lo.z, lo.w, hi.x, hi.y, hi.z, hi.w};
        unsigned short rv[8] = {rl.x, rl.y, rl.z, rl.w, rh.x, rh.y, rh.z, rh.w};
        int c0 = kc * 32 + q * 8;
        float4 sc0 = *(const float4*)&ssl[c0];
        float4 sc1 = *(const float4*)&ssl[c0 + 4];
        float4 sh0 = *(const float4*)&ssl[128 + c0];
        float4 sh1 = *(const float4*)&ssl[128 + c0 + 4];
        float scv[8] = {sc0.x, sc0.y, sc0.z, sc0.w, sc1.x, sc1.y, sc1.z, sc1.w};
        float shv[8] = {sh0.x, sh0.y, sh0.z, sh0.w, sh1.x, sh1.y, sh1.z, sh1.w};
#pragma unroll
        for (int j = 0; j < 8; j++) {
            float yy = fmaxf(bf2f(av[j]) * scv[j] + shv[j], 0.f) + bf2f(rv[j]);
            y[kc][j] = yy; sq += yy * yy;
        }
    }
    sq += __shfl_xor(sq, 16, 64);
    sq += __shfl_xor(sq, 32, 64);
    float inv = 1.f / fmaxf(sqrtf(sq), L2_EPS);

    bf16x8 af[4];
#pragma unroll
    for (int kc = 0; kc < 4; kc++) {
        unsigned short t[8];
#pragma unroll
        for (int j = 0; j < 8; j++) t[j] = f2bf(y[kc][j] * inv);
        af[kc] = *(const bf16x8*)t;
    }

    f32x4 acc[3];
#pragma unroll
    for (int cc = 0; cc < 3; cc++) acc[cc] = (f32x4){0.f, 0.f, 0.f, 0.f};
#pragma unroll
    for (int kc = 0; kc < 4; kc++)
#pragma unroll
        for (int cc = 0; cc < 3; cc++) {
            bf16x8 b = *(const bf16x8*)&Ws[(size_t)((kc * 3 + cc) * 64 + lane) * 8];
            acc[cc] = __builtin_amdgcn_mfma_f32_16x16x32_bf16(af[kc], b, acc[cc], 0, 0, 0);
        }

#pragma unroll
    for (int cc = 0; cc < 3; cc++) {
        int col = cc * 16 + m;
        if (col < COUT) {
            float bb = bout[col];
#pragma unroll
            for (int i = 0; i < 4; i++) {
                int r = R0 + q * 4 + i;
                if (r < nrows) C[(size_t)r * COUT + col] = acc[cc][i] + bb;
            }
        }
    }
}

// ---------------- host ----------------

extern "C" void kernel_launch(void* const* d_in, const int* in_sizes, int n_in,
                              void* d_out, int out_size, void* d_ws, size_t ws_size,
                              hipStream_t stream) {
    const float* x    = (const float*)d_in[0];
    const int*   ei   = (const int*)d_in[1];
    const float* W1   = (const float*)d_in[2];
    const float* b1   = (const float*)d_in[3];
    const float* W2   = (const float*)d_in[4];
    const float* b2   = (const float*)d_in[5];
    const float* W3   = (const float*)d_in[6];
    const float* b3   = (const float*)d_in[7];
    const float* g1   = (const float*)d_in[8];
    const float* be1  = (const float*)d_in[9];
    const float* g2   = (const float*)d_in[10];
    const float* be2  = (const float*)d_in[11];
    const float* g3   = (const float*)d_in[12];
    const float* be3  = (const float*)d_in[13];
    const float* Wout = (const float*)d_in[14];
    const float* bout = (const float*)d_in[15];
    float* out = (float*)d_out;

    const int N = in_sizes[0] / DD;
    const int E = in_sizes[1] / 2;
    const int SSTRIDE = NREP * 256;          // floats per layer's stats

    // workspace layout
    char* w = (char*)d_ws;
    unsigned short* linb = (unsigned short*)w; w += (size_t)N * DD * sizeof(unsigned short);
    unsigned short* aggA = (unsigned short*)w; w += (size_t)N * DD * sizeof(unsigned short);
    unsigned short* aggB = (unsigned short*)w; w += (size_t)N * DD * sizeof(unsigned short);
    unsigned short* hbf1 = (unsigned short*)w; w += (size_t)N * DD * sizeof(unsigned short);
    unsigned short* hbf2 = (unsigned short*)w; w += (size_t)N * DD * sizeof(unsigned short);
    unsigned short* wb   = (unsigned short*)w; w += 3 * 16384 * sizeof(unsigned short);
    unsigned short* wob  = (unsigned short*)w; w += 6144 * sizeof(unsigned short);
    int* perm    = (int*)w;                    w += (size_t)E * sizeof(int);
    int* pord    = (int*)w;                    w += (size_t)E * sizeof(int);
    int* deg     = (int*)w;                    w += (size_t)N * sizeof(int);
    int* row_ptr = (int*)w;                    w += (size_t)(N + 1) * sizeof(int);
    float* dinv  = (float*)w;                  w += (size_t)N * sizeof(float);
    int* bsum    = (int*)w;                    w += 512 * sizeof(int);
    int* boff    = (int*)w;                    w += 512 * sizeof(int);
    float* stats = (float*)w;                  w += 3 * (size_t)SSTRIDE * sizeof(float);

    const int NB = (N + 1 + 255) / 256;      // scan blocks

    // ---- CSR build + weight repack (deg/stats zeroed inside wrepack) ----
    k_wrepack_all<<<35, 256, 0, stream>>>(W1, W2, W3, Wout, wb, wob, stats, deg, N);
    k_hist<<<(E + 255) / 256, 256, 0, stream>>>(ei, E, deg, pord);
    k_scan_a<<<NB, 256, 0, stream>>>(deg, row_ptr, bsum, dinv, N);
    k_scan_b<<<1, 512, 0, stream>>>(bsum, boff, NB);
    k_fill<<<(E + 255) / 256, 256, 0, stream>>>(ei, pord, E, row_ptr, boff, perm);

    int gemmGrid = (N + 63) / 64;
    int aggGrid = (N + 7) / 8;               // one node per half-wave
    float inv_n = 1.0f / (float)N;

    // ---- layer 1 ----
    k_gemm0<<<gemmGrid, 256, 0, stream>>>(x, wb, dinv, linb, N);
    k_aggs<<<aggGrid, 256, 0, stream>>>(linb, row_ptr, boff, perm, dinv, b1, aggA, stats, N);
    // ---- layer 2 (post1 fused into gemm2) ----
    k_fused<false><<<gemmGrid, 256, 0, stream>>>(aggA, stats, g1, be1, inv_n,
                                                 nullptr, wb + 16384, dinv, hbf1, linb, N);
    k_aggs<<<aggGrid, 256, 0, stream>>>(linb, row_ptr, boff, perm, dinv, b2, aggB,
                                        stats + SSTRIDE, N);
    // ---- layer 3 (post2 fused into gemm3) ----
    k_fused<true><<<gemmGrid, 256, 0, stream>>>(aggB, stats + SSTRIDE, g2, be2, inv_n,
                                                hbf1, wb + 32768, dinv, hbf2, linb, N);
    k_aggs<<<aggGrid, 256, 0, stream>>>(linb, row_ptr, boff, perm, dinv, b3, aggA,
                                        stats + 2 * SSTRIDE, N);
    // ---- output (post3 fused into output GEMM) ----
    k_outfused<<<gemmGrid, 256, 0, stream>>>(aggA, stats + 2 * SSTRIDE, g3, be3, inv_n,
                                             hbf2, wob, bout, out, N);
}